// Round 12
// baseline (267.805 us; speedup 1.0000x reference)
//
#include <hip/hip_runtime.h>

#define B_ 8
#define N_ 20000
#define M_ 1024
#define C_ 128
#define S_ 64
#define NCH_ 131    // 3 + C
#define GD_ 7       // grid cells per axis
#define NC_ (GD_*GD_*GD_)   // 343 cells
#define SCALE_ 3.2f // bin width 0.3125 > r=0.3  -> +/-1 cell guarantee strict
#define NW_ 626     // u32 bitmap words per center (20000/32 = 625, +1 pad)
#define NWP_ 640    // padded per-wave bitmap stride

// INSTRUMENTATION: repeat query body to surface it in rocprof top-5 with
// counters (idempotent recompute). Set to 1 to restore production behavior.
#define QREP_ 10

typedef float  vf4 __attribute__((ext_vector_type(4)));  // nontemporal-compatible 16B

__device__ __forceinline__ int cell_of(float x, float y, float z) {
    const int ix = (int)(x * SCALE_);
    const int iy = (int)(y * SCALE_);
    const int iz = (int)(z * SCALE_);
    return (ix * GD_ + iy) * GD_ + iz;
}

// ---- K0: bucket points by cell (per batch): counts -> prefix -> scatter ----
__global__ __launch_bounds__(1024) void build_grid(
    const float* __restrict__ xyz,   // (B, N, 3)
    float4* __restrict__ pts4,       // (B, N) packed (x,y,z,orig_idx)
    int* __restrict__ cst)           // (B, 344) cell starts
{
    const int b   = blockIdx.x;
    const int tid = threadIdx.x;
    __shared__ int hcnt[NC_];
    __shared__ int hstart[NC_ + 1];

    if (tid < NC_) hcnt[tid] = 0;
    __syncthreads();

    const float* xb = xyz + (size_t)b * N_ * 3;
    for (int i = tid; i < N_; i += 1024) {
        const float x = xb[3*i], y = xb[3*i+1], z = xb[3*i+2];
        atomicAdd(&hcnt[cell_of(x, y, z)], 1);
    }
    __syncthreads();

    if (tid == 0) {
        int run = 0;
        for (int c = 0; c < NC_; ++c) { hstart[c] = run; run += hcnt[c]; }
        hstart[NC_] = run;   // == N_
    }
    __syncthreads();

    if (tid < NC_ + 1) cst[b * (NC_ + 1) + tid] = hstart[tid];
    if (tid < NC_) hcnt[tid] = hstart[tid];   // write cursors
    __syncthreads();

    for (int i = tid; i < N_; i += 1024) {
        const float x = xb[3*i], y = xb[3*i+1], z = xb[3*i+2];
        const int slot = atomicAdd(&hcnt[cell_of(x, y, z)], 1);
        float4 p; p.x = x; p.y = y; p.z = z; p.w = __int_as_float(i);
        pts4[(size_t)b * N_ + slot] = p;
    }
}

// ---- K1: ball query via grid + per-wave LDS hit-bitmap ---------------------
// 1024 blocks x 512 threads (8 waves); wave = one center.
__global__ __launch_bounds__(512) void query_kernel(
    const float* __restrict__ xyz,       // (B, N, 3) for grouped-xyz output
    const float* __restrict__ new_xyz,   // (B, M, 3)
    const float4* __restrict__ pts4,     // (B, N) cell-sorted
    const int* __restrict__ cst,         // (B, 344)
    float* __restrict__ out,
    int* __restrict__ iws)               // (B, M, S)
{
    const int tid  = threadIdx.x;
    const int w    = tid >> 6;
    const int lane = tid & 63;
    const int bm   = blockIdx.x * 8 + w;
    const int b    = bm >> 10;
    const int m    = bm & (M_ - 1);

    __shared__ unsigned bmap[8][NWP_];   // 8 x 2560 B wave-private bitmaps
    __shared__ int s_widx[8][S_];

    for (int rep_ = 0; rep_ < QREP_; ++rep_) {   // INSTRUMENTATION loop

    // zero own bitmap (wave-private, no barrier needed)
    for (int k = lane; k < NWP_; k += 64) bmap[w][k] = 0u;

    const float cx = new_xyz[bm * 3 + 0];
    const float cy = new_xyz[bm * 3 + 1];
    const float cz = new_xyz[bm * 3 + 2];
    const float r2 = (float)(0.3 * 0.3);

    const int ix = (int)(cx * SCALE_);
    const int iy = (int)(cy * SCALE_);
    const int iz = (int)(cz * SCALE_);
    const int x0 = ix > 0 ? ix - 1 : 0, x1 = ix < GD_-1 ? ix + 1 : GD_-1;
    const int y0 = iy > 0 ? iy - 1 : 0, y1 = iy < GD_-1 ? iy + 1 : GD_-1;
    const int z0 = iz > 0 ? iz - 1 : 0, z1 = iz < GD_-1 ? iz + 1 : GD_-1;

    const float4* pb = pts4 + (size_t)b * N_;
    const int* cb = cst + b * (NC_ + 1);

    // mark phase: test points of <=27 neighbor cells (z-run contiguous)
    for (int xx = x0; xx <= x1; ++xx) {
        for (int yy = y0; yy <= y1; ++yy) {
            const int cid = (xx * GD_ + yy) * GD_;
            const int s = cb[cid + z0];
            const int e = cb[cid + z1 + 1];
            for (int i = s + lane; i < e; i += 64) {
                const float4 p = pb[i];
                // match numpy f32 rounding exactly: no FMA contraction
                const float dx = __fadd_rn(p.x, -cx);
                const float dy = __fadd_rn(p.y, -cy);
                const float dz = __fadd_rn(p.z, -cz);
                const float d2 = __fadd_rn(
                    __fadd_rn(__fmul_rn(dx, dx), __fmul_rn(dy, dy)),
                    __fmul_rn(dz, dz));
                if (d2 < r2) {
                    const int po = __float_as_int(p.w);
                    atomicOr(&bmap[w][po >> 5], 1u << (po & 31));
                }
            }
        }
    }

    // extract phase: first 64 set bits ascending (== first 64 indices in order)
    int cnt = 0;
    for (int base = 0; base < NW_ && cnt < S_; base += 64) {
        const int wi = base + lane;
        const unsigned wv = (wi < NW_) ? bmap[w][wi] : 0u;
        const int c = __popc(wv);
        int p = c;
#pragma unroll
        for (int o = 1; o < 64; o <<= 1) {
            const int t = __shfl_up(p, o);
            if (lane >= o) p += t;
        }
        const int tot = __shfl(p, 63);
        int r = cnt + p - c;             // exclusive prefix rank
        unsigned ww = wv;
        while (ww && r < S_) {
            const int bit = __ffs(ww) - 1;
            s_widx[w][r] = wi * 32 + bit;
            ++r;
            ww &= ww - 1;
        }
        cnt += tot;
    }

    // pad slots beyond cnt with first valid index (0 if none)
    {
        const int c = cnt < S_ ? cnt : S_;
        const int first = (c > 0) ? s_widx[w][0] : 0;
        if (lane >= c) s_widx[w][lane] = first;
    }

    const int n = s_widx[w][lane];
    const float* xb = xyz + (size_t)b * N_ * 3;

    // idx outputs (float copy in d_out, int copy for K2 -- keep iws L2-hot)
    float* out_idx = out + (size_t)B_ * NCH_ * M_ * S_;
    __builtin_nontemporal_store((float)n, &out_idx[(size_t)bm * S_ + lane]);
    iws[(size_t)bm * S_ + lane] = n;

    // grouped relative xyz -> channels 0..2 (xyz slice L2-hot)
    const float px = xb[n * 3 + 0];
    const float py = xb[n * 3 + 1];
    const float pz = xb[n * 3 + 2];
    __builtin_nontemporal_store((px - cx) / 0.3f,
        &out[(((size_t)b * NCH_ + 0) * M_ + m) * S_ + lane]);
    __builtin_nontemporal_store((py - cy) / 0.3f,
        &out[(((size_t)b * NCH_ + 1) * M_ + m) * S_ + lane]);
    __builtin_nontemporal_store((pz - cz) / 0.3f,
        &out[(((size_t)b * NCH_ + 2) * M_ + m) * S_ + lane]);

    }   // end INSTRUMENTATION loop
}

// ---- K2: per (b,ch) block -- stage 80KB channel slice in LDS, gather-write -
__global__ __launch_bounds__(256) void group_feat_kernel(
    const float* __restrict__ features,  // (B, C, N)
    const int* __restrict__ iws,         // (B, M, S)
    float* __restrict__ out)
{
    // b = blockIdx & 7: round-robin dispatch pins each batch to one XCD,
    // keeping that batch's idx slice (256 KB) L2-resident.
    const int b  = blockIdx.x & 7;
    const int ch = blockIdx.x >> 3;

    __shared__ float slice[N_];          // 80000 B (gfx950: >64KB LDS ok)

    const float* fb = features + ((size_t)b * C_ + ch) * N_;
    const vf4* fb4 = (const vf4*)fb;
    vf4* sl4 = (vf4*)slice;
    for (int i = threadIdx.x; i < N_ / 4; i += 256)
        sl4[i] = __builtin_nontemporal_load(&fb4[i]);  // read-once stream
    __syncthreads();

    const int* ib = iws + (size_t)b * M_ * S_;
    float* ob = out + ((size_t)b * NCH_ + 3 + ch) * (size_t)(M_ * S_);
    // 4 elems/thread: int4 idx load + float4 nontemporal store (streamed out)
    for (int e = threadIdx.x * 4; e < M_ * S_; e += 256 * 4) {
        const int4 ii = *(const int4*)(ib + e);
        vf4 w;
        w.x = slice[ii.x]; w.y = slice[ii.y];
        w.z = slice[ii.z]; w.w = slice[ii.w];
        __builtin_nontemporal_store(w, (vf4*)(ob + e));
    }
}

// ---- Fallback: round-1 fused kernel (if ws too small) ----------------------
__global__ __launch_bounds__(256) void qg_fused(
    const float* __restrict__ xyz,
    const float* __restrict__ new_xyz,
    const float* __restrict__ features,
    float* __restrict__ out)
{
    const int bm = blockIdx.x;
    const int b  = bm >> 10;
    const int m  = bm & (M_ - 1);
    const int tid = threadIdx.x;

    __shared__ int s_idx[S_];

    if (tid < 64) {
        const int lane = tid;
        const float cx = new_xyz[bm * 3 + 0];
        const float cy = new_xyz[bm * 3 + 1];
        const float cz = new_xyz[bm * 3 + 2];
        const float r2 = (float)(0.3 * 0.3);
        const float* xb = xyz + (size_t)b * N_ * 3;

        int cnt = 0;
        for (int base = 0; base < N_; base += 64) {
            const int n = base + lane;
            bool valid = false;
            if (n < N_) {
                const float dx = __fadd_rn(xb[n * 3 + 0], -cx);
                const float dy = __fadd_rn(xb[n * 3 + 1], -cy);
                const float dz = __fadd_rn(xb[n * 3 + 2], -cz);
                const float d2 = __fadd_rn(
                    __fadd_rn(__fmul_rn(dx, dx), __fmul_rn(dy, dy)),
                    __fmul_rn(dz, dz));
                valid = d2 < r2;
            }
            const unsigned long long mk = __ballot(valid);
            if (valid) {
                const int pos = cnt + __popcll(mk & ((1ull << lane) - 1ull));
                if (pos < S_) s_idx[pos] = n;
            }
            cnt += __popcll(mk);
            if (cnt >= S_) break;
        }
        const int c = cnt < S_ ? cnt : S_;
        const int first = (c > 0) ? s_idx[0] : 0;
        if (lane >= c) s_idx[lane] = first;

        float* out_idx = out + (size_t)B_ * NCH_ * M_ * S_;
        out_idx[(size_t)bm * S_ + lane] = (float)s_idx[lane];
    }
    __syncthreads();

    if (tid < 3 * S_) {
        const int ch = tid >> 6;
        const int s  = tid & 63;
        const int n  = s_idx[s];
        const float v = (xyz[((size_t)b * N_ + n) * 3 + ch] - new_xyz[bm * 3 + ch]) / 0.3f;
        out[(((size_t)b * NCH_ + ch) * M_ + m) * S_ + s] = v;
    }

    const int s  = tid & 63;
    const int cq = tid >> 6;
    const int n  = s_idx[s];
    const float* fb = features + (size_t)b * C_ * N_;
    float* ob = out + (((size_t)b * NCH_ + 3) * M_ + m) * S_ + s;
    for (int ch = cq; ch < C_; ch += 4) {
        ob[(size_t)ch * (M_ * S_)] = fb[(size_t)ch * N_ + n];
    }
}

extern "C" void kernel_launch(void* const* d_in, const int* in_sizes, int n_in,
                              void* d_out, int out_size, void* d_ws, size_t ws_size,
                              hipStream_t stream) {
    const float* xyz      = (const float*)d_in[0];
    const float* new_xyz  = (const float*)d_in[1];
    // d_in[2] = batch_distances, d_in[3] = inds : acceleration hints only, unused
    const float* features = (const float*)d_in[4];
    float* out = (float*)d_out;

    // ws layout: pts4 (B*N float4) | cst (B*344 int) | iws (B*M*S int)
    const size_t pts4_elems = (size_t)B_ * N_;
    const size_t cst_elems  = (size_t)B_ * (NC_ + 1);
    const size_t iws_elems  = (size_t)B_ * M_ * S_;
    const size_t need = pts4_elems * 16 + (cst_elems + iws_elems) * 4;

    if (ws_size < need) {
        qg_fused<<<B_ * M_, 256, 0, stream>>>(xyz, new_xyz, features, out);
        return;
    }
    float4* pts4 = (float4*)d_ws;
    int*    cst  = (int*)(pts4 + pts4_elems);
    int*    iws  = cst + cst_elems;

    build_grid<<<B_, 1024, 0, stream>>>(xyz, pts4, cst);
    query_kernel<<<(B_ * M_) / 8, 512, 0, stream>>>(xyz, new_xyz, pts4, cst, out, iws);
    group_feat_kernel<<<B_ * C_, 256, 0, stream>>>(features, iws, out);
}

// Round 13
// 133.564 us; speedup vs baseline: 2.0051x; 2.0051x over previous
//
#include <hip/hip_runtime.h>

#define B_ 8
#define N_ 20000
#define M_ 1024
#define C_ 128
#define S_ 64
#define NCH_ 131    // 3 + C
#define GD_ 7       // grid cells per axis
#define NC_ (GD_*GD_*GD_)   // 343 cells
#define SCALE_ 3.2f // bin width 0.3125 > r=0.3  -> +/-1 cell guarantee strict
#define NW_ 626     // u32 bitmap words per center (20000/32 = 625, +1 pad)
#define NWP_ 640    // padded per-wave bitmap stride
#define SLICES_ 8   // point slices per batch for grid build
#define SLPTS_ (N_ / SLICES_)   // 2500

typedef float  vf4 __attribute__((ext_vector_type(4)));  // nontemporal-compatible 16B

__device__ __forceinline__ int cell_of(float x, float y, float z) {
    const int ix = (int)(x * SCALE_);
    const int iy = (int)(y * SCALE_);
    const int iz = (int)(z * SCALE_);
    return (ix * GD_ + iy) * GD_ + iz;
}

// ---- K0a: per-(batch,slice) cell counts into private rows (no gl. atomics) -
__global__ __launch_bounds__(256) void grid_count(
    const float* __restrict__ xyz,   // (B, N, 3)
    int* __restrict__ part)          // (64, 343)
{
    const int blk = blockIdx.x;      // 64 = B_ * SLICES_
    const int b = blk >> 3, s = blk & 7;
    __shared__ int h[NC_];
    for (int i = threadIdx.x; i < NC_; i += 256) h[i] = 0;
    __syncthreads();

    const float* xb = xyz + (size_t)b * N_ * 3;
    const int p0 = s * SLPTS_, p1 = p0 + SLPTS_;
    for (int i = p0 + threadIdx.x; i < p1; i += 256)
        atomicAdd(&h[cell_of(xb[3*i], xb[3*i+1], xb[3*i+2])], 1);
    __syncthreads();

    int* pr = part + blk * NC_;
    for (int i = threadIdx.x; i < NC_; i += 256) pr[i] = h[i];
}

// ---- K0b: reduce 8 slices + wave-parallel exclusive scan per batch ---------
__global__ __launch_bounds__(512) void grid_scan(
    const int* __restrict__ part,    // (64, 343)
    int* __restrict__ cst,           // (B, 344)
    int* __restrict__ cur)           // (B, 343) scatter cursors
{
    const int w = threadIdx.x >> 6, lane = threadIdx.x & 63;  // wave w = batch w
    int run = 0;
    for (int c0 = 0; c0 < NC_; c0 += 64) {
        const int idx = c0 + lane;
        int v = 0;
        if (idx < NC_) {
#pragma unroll
            for (int s = 0; s < SLICES_; ++s) v += part[(w*SLICES_+s)*NC_ + idx];
        }
        int sc = v;
#pragma unroll
        for (int o = 1; o < 64; o <<= 1) {
            const int t = __shfl_up(sc, o);
            if (lane >= o) sc += t;
        }
        const int excl = run + sc - v;
        if (idx < NC_) { cst[w*(NC_+1)+idx] = excl; cur[w*NC_+idx] = excl; }
        run += __shfl(sc, 63);
    }
    if (lane == 0) cst[w*(NC_+1)+NC_] = run;   // == N_
}

// ---- K0c: scatter points to cell-sorted layout (order in cell irrelevant) --
__global__ __launch_bounds__(256) void grid_scatter(
    const float* __restrict__ xyz,
    int* __restrict__ cur,           // (B, 343)
    float4* __restrict__ pts4)       // (B, N) packed (x,y,z,orig_idx)
{
    const int blk = blockIdx.x;
    const int b = blk >> 3, s = blk & 7;
    const float* xb = xyz + (size_t)b * N_ * 3;
    const int p0 = s * SLPTS_, p1 = p0 + SLPTS_;
    for (int i = p0 + threadIdx.x; i < p1; i += 256) {
        const float x = xb[3*i], y = xb[3*i+1], z = xb[3*i+2];
        const int slot = atomicAdd(&cur[b*NC_ + cell_of(x, y, z)], 1);
        float4 p; p.x = x; p.y = y; p.z = z; p.w = __int_as_float(i);
        pts4[(size_t)b * N_ + slot] = p;
    }
}

// ---- K1: ball query via grid + per-wave LDS hit-bitmap ---------------------
// 1024 blocks x 512 threads (8 waves); wave = one center.
__global__ __launch_bounds__(512) void query_kernel(
    const float* __restrict__ xyz,       // (B, N, 3) for grouped-xyz output
    const float* __restrict__ new_xyz,   // (B, M, 3)
    const float4* __restrict__ pts4,     // (B, N) cell-sorted
    const int* __restrict__ cst,         // (B, 344)
    float* __restrict__ out,
    int* __restrict__ iws)               // (B, M, S)
{
    const int tid  = threadIdx.x;
    const int w    = tid >> 6;
    const int lane = tid & 63;
    const int bm   = blockIdx.x * 8 + w;
    const int b    = bm >> 10;
    const int m    = bm & (M_ - 1);

    __shared__ unsigned bmap[8][NWP_];   // 8 x 2560 B wave-private bitmaps
    __shared__ int s_widx[8][S_];

    // zero own bitmap (wave-private, no barrier needed)
    for (int k = lane; k < NWP_; k += 64) bmap[w][k] = 0u;

    const float cx = new_xyz[bm * 3 + 0];
    const float cy = new_xyz[bm * 3 + 1];
    const float cz = new_xyz[bm * 3 + 2];
    const float r2 = (float)(0.3 * 0.3);

    const int ix = (int)(cx * SCALE_);
    const int iy = (int)(cy * SCALE_);
    const int iz = (int)(cz * SCALE_);
    const int x0 = ix > 0 ? ix - 1 : 0, x1 = ix < GD_-1 ? ix + 1 : GD_-1;
    const int y0 = iy > 0 ? iy - 1 : 0, y1 = iy < GD_-1 ? iy + 1 : GD_-1;
    const int z0 = iz > 0 ? iz - 1 : 0, z1 = iz < GD_-1 ? iz + 1 : GD_-1;

    const float4* pb = pts4 + (size_t)b * N_;
    const int* cb = cst + b * (NC_ + 1);

    // mark phase: test points of <=27 neighbor cells (z-run contiguous)
    for (int xx = x0; xx <= x1; ++xx) {
        for (int yy = y0; yy <= y1; ++yy) {
            const int cid = (xx * GD_ + yy) * GD_;
            const int s = cb[cid + z0];
            const int e = cb[cid + z1 + 1];
            for (int i = s + lane; i < e; i += 64) {
                const float4 p = pb[i];
                // match numpy f32 rounding exactly: no FMA contraction
                const float dx = __fadd_rn(p.x, -cx);
                const float dy = __fadd_rn(p.y, -cy);
                const float dz = __fadd_rn(p.z, -cz);
                const float d2 = __fadd_rn(
                    __fadd_rn(__fmul_rn(dx, dx), __fmul_rn(dy, dy)),
                    __fmul_rn(dz, dz));
                if (d2 < r2) {
                    const int po = __float_as_int(p.w);
                    atomicOr(&bmap[w][po >> 5], 1u << (po & 31));
                }
            }
        }
    }

    // extract phase: first 64 set bits ascending (== first 64 indices in order)
    int cnt = 0;
    for (int base = 0; base < NW_ && cnt < S_; base += 64) {
        const int wi = base + lane;
        const unsigned wv = (wi < NW_) ? bmap[w][wi] : 0u;
        const int c = __popc(wv);
        int p = c;
#pragma unroll
        for (int o = 1; o < 64; o <<= 1) {
            const int t = __shfl_up(p, o);
            if (lane >= o) p += t;
        }
        const int tot = __shfl(p, 63);
        int r = cnt + p - c;             // exclusive prefix rank
        unsigned ww = wv;
        while (ww && r < S_) {
            const int bit = __ffs(ww) - 1;
            s_widx[w][r] = wi * 32 + bit;
            ++r;
            ww &= ww - 1;
        }
        cnt += tot;
    }

    // pad slots beyond cnt with first valid index (0 if none)
    {
        const int c = cnt < S_ ? cnt : S_;
        const int first = (c > 0) ? s_widx[w][0] : 0;
        if (lane >= c) s_widx[w][lane] = first;
    }

    const int n = s_widx[w][lane];
    const float* xb = xyz + (size_t)b * N_ * 3;

    // idx outputs (float copy in d_out, int copy for K2 -- keep iws L2-hot)
    float* out_idx = out + (size_t)B_ * NCH_ * M_ * S_;
    __builtin_nontemporal_store((float)n, &out_idx[(size_t)bm * S_ + lane]);
    iws[(size_t)bm * S_ + lane] = n;

    // grouped relative xyz -> channels 0..2 (xyz slice L2-hot)
    const float px = xb[n * 3 + 0];
    const float py = xb[n * 3 + 1];
    const float pz = xb[n * 3 + 2];
    __builtin_nontemporal_store((px - cx) / 0.3f,
        &out[(((size_t)b * NCH_ + 0) * M_ + m) * S_ + lane]);
    __builtin_nontemporal_store((py - cy) / 0.3f,
        &out[(((size_t)b * NCH_ + 1) * M_ + m) * S_ + lane]);
    __builtin_nontemporal_store((pz - cz) / 0.3f,
        &out[(((size_t)b * NCH_ + 2) * M_ + m) * S_ + lane]);
}

// ---- K2: per (b,ch) block -- stage 80KB channel slice in LDS, gather-write -
__global__ __launch_bounds__(256) void group_feat_kernel(
    const float* __restrict__ features,  // (B, C, N)
    const int* __restrict__ iws,         // (B, M, S)
    float* __restrict__ out)
{
    // b = blockIdx & 7: round-robin dispatch pins each batch to one XCD,
    // keeping that batch's idx slice (256 KB) L2-resident.
    const int b  = blockIdx.x & 7;
    const int ch = blockIdx.x >> 3;

    __shared__ float slice[N_];          // 80000 B (gfx950: >64KB LDS ok)

    const float* fb = features + ((size_t)b * C_ + ch) * N_;
    const vf4* fb4 = (const vf4*)fb;
    vf4* sl4 = (vf4*)slice;
    for (int i = threadIdx.x; i < N_ / 4; i += 256)
        sl4[i] = __builtin_nontemporal_load(&fb4[i]);  // read-once stream
    __syncthreads();

    const int* ib = iws + (size_t)b * M_ * S_;
    float* ob = out + ((size_t)b * NCH_ + 3 + ch) * (size_t)(M_ * S_);
    // 4 elems/thread: int4 idx load + float4 nontemporal store (streamed out)
    for (int e = threadIdx.x * 4; e < M_ * S_; e += 256 * 4) {
        const int4 ii = *(const int4*)(ib + e);
        vf4 w;
        w.x = slice[ii.x]; w.y = slice[ii.y];
        w.z = slice[ii.z]; w.w = slice[ii.w];
        __builtin_nontemporal_store(w, (vf4*)(ob + e));
    }
}

// ---- Fallback: round-1 fused kernel (if ws too small) ----------------------
__global__ __launch_bounds__(256) void qg_fused(
    const float* __restrict__ xyz,
    const float* __restrict__ new_xyz,
    const float* __restrict__ features,
    float* __restrict__ out)
{
    const int bm = blockIdx.x;
    const int b  = bm >> 10;
    const int m  = bm & (M_ - 1);
    const int tid = threadIdx.x;

    __shared__ int s_idx[S_];

    if (tid < 64) {
        const int lane = tid;
        const float cx = new_xyz[bm * 3 + 0];
        const float cy = new_xyz[bm * 3 + 1];
        const float cz = new_xyz[bm * 3 + 2];
        const float r2 = (float)(0.3 * 0.3);
        const float* xb = xyz + (size_t)b * N_ * 3;

        int cnt = 0;
        for (int base = 0; base < N_; base += 64) {
            const int n = base + lane;
            bool valid = false;
            if (n < N_) {
                const float dx = __fadd_rn(xb[n * 3 + 0], -cx);
                const float dy = __fadd_rn(xb[n * 3 + 1], -cy);
                const float dz = __fadd_rn(xb[n * 3 + 2], -cz);
                const float d2 = __fadd_rn(
                    __fadd_rn(__fmul_rn(dx, dx), __fmul_rn(dy, dy)),
                    __fmul_rn(dz, dz));
                valid = d2 < r2;
            }
            const unsigned long long mk = __ballot(valid);
            if (valid) {
                const int pos = cnt + __popcll(mk & ((1ull << lane) - 1ull));
                if (pos < S_) s_idx[pos] = n;
            }
            cnt += __popcll(mk);
            if (cnt >= S_) break;
        }
        const int c = cnt < S_ ? cnt : S_;
        const int first = (c > 0) ? s_idx[0] : 0;
        if (lane >= c) s_idx[lane] = first;

        float* out_idx = out + (size_t)B_ * NCH_ * M_ * S_;
        out_idx[(size_t)bm * S_ + lane] = (float)s_idx[lane];
    }
    __syncthreads();

    if (tid < 3 * S_) {
        const int ch = tid >> 6;
        const int s  = tid & 63;
        const int n  = s_idx[s];
        const float v = (xyz[((size_t)b * N_ + n) * 3 + ch] - new_xyz[bm * 3 + ch]) / 0.3f;
        out[(((size_t)b * NCH_ + ch) * M_ + m) * S_ + s] = v;
    }

    const int s  = tid & 63;
    const int cq = tid >> 6;
    const int n  = s_idx[s];
    const float* fb = features + (size_t)b * C_ * N_;
    float* ob = out + (((size_t)b * NCH_ + 3) * M_ + m) * S_ + s;
    for (int ch = cq; ch < C_; ch += 4) {
        ob[(size_t)ch * (M_ * S_)] = fb[(size_t)ch * N_ + n];
    }
}

extern "C" void kernel_launch(void* const* d_in, const int* in_sizes, int n_in,
                              void* d_out, int out_size, void* d_ws, size_t ws_size,
                              hipStream_t stream) {
    const float* xyz      = (const float*)d_in[0];
    const float* new_xyz  = (const float*)d_in[1];
    // d_in[2] = batch_distances, d_in[3] = inds : acceleration hints only, unused
    const float* features = (const float*)d_in[4];
    float* out = (float*)d_out;

    // ws layout: pts4 (B*N float4) | cst (B*344) | cur (B*343) | part (64*343) | iws
    const size_t pts4_elems = (size_t)B_ * N_;
    const size_t cst_elems  = (size_t)B_ * (NC_ + 1);
    const size_t cur_elems  = (size_t)B_ * NC_;
    const size_t part_elems = (size_t)B_ * SLICES_ * NC_;
    const size_t iws_elems  = (size_t)B_ * M_ * S_;
    const size_t need = pts4_elems * 16 +
                        (cst_elems + cur_elems + part_elems + iws_elems) * 4;

    if (ws_size < need) {
        qg_fused<<<B_ * M_, 256, 0, stream>>>(xyz, new_xyz, features, out);
        return;
    }
    float4* pts4 = (float4*)d_ws;
    int*    cst  = (int*)(pts4 + pts4_elems);
    int*    cur  = cst + cst_elems;
    int*    part = cur + cur_elems;
    int*    iws  = part + part_elems;

    grid_count  <<<B_ * SLICES_, 256, 0, stream>>>(xyz, part);
    grid_scan   <<<1, 512, 0, stream>>>(part, cst, cur);
    grid_scatter<<<B_ * SLICES_, 256, 0, stream>>>(xyz, cur, pts4);
    query_kernel<<<(B_ * M_) / 8, 512, 0, stream>>>(xyz, new_xyz, pts4, cst, out, iws);
    group_feat_kernel<<<B_ * C_, 256, 0, stream>>>(features, iws, out);
}